// Round 6
// baseline (598.313 us; speedup 1.0000x reference)
//
#include <hip/hip_runtime.h>

#define HID 3584
#define RDIM 224
#define BM 64

typedef __attribute__((ext_vector_type(8))) short short8;
typedef __attribute__((ext_vector_type(8))) unsigned short ushort8;
typedef __attribute__((ext_vector_type(4))) unsigned short ushort4v;
typedef __attribute__((ext_vector_type(4))) float f32x4;

// round-to-nearest-even f32 -> bf16 bit pattern (data is finite; no NaN path)
static __device__ __forceinline__ unsigned short f2bf(float f) {
  unsigned int u = __float_as_uint(f);
  u += 0x7fffu + ((u >> 16) & 1u);
  return (unsigned short)(u >> 16);
}

// one-shot fp32 -> bf16 conversion of both weight matrices into d_ws so the
// main kernel's per-block weight streams fit in a single XCD L2 (3.2 MB bf16)
__global__ __launch_bounds__(256) void prep_weights(
    const float* __restrict__ wdf, const float* __restrict__ wuf,
    unsigned short* __restrict__ wdb, unsigned short* __restrict__ wub) {
  const int Q = (RDIM * HID) / 4;  // 200704 float4 per matrix
  int idx = blockIdx.x * 256 + threadIdx.x;
  const float4* src;
  unsigned short* dst;
  int j;
  if (idx < Q) {
    src = reinterpret_cast<const float4*>(wdf); dst = wdb; j = idx;
  } else {
    src = reinterpret_cast<const float4*>(wuf); dst = wub; j = idx - Q;
  }
  float4 v = src[j];
  ushort4v o;
  o.x = f2bf(v.x); o.y = f2bf(v.y); o.z = f2bf(v.z); o.w = f2bf(v.w);
  *reinterpret_cast<ushort4v*>(dst + (size_t)j * 4) = o;
}

// Fully fused: LN -> down(224) -> GELU -> up(3584) -> x + alpha*res
// 512 threads (8 waves), BM=64 tokens/block, grid = 16384/64 = 256 blocks.
__global__ __launch_bounds__(512, 4) void fused_adapter(
    const float* __restrict__ x,
    const float* __restrict__ gamma,
    const float* __restrict__ beta,
    const unsigned short* __restrict__ wd,   // bf16 [224][3584]  (B^T for GEMM1)
    const unsigned short* __restrict__ wu,   // bf16 [3584][224]  (B^T for GEMM2)
    const float* __restrict__ alpha_p,
    float* __restrict__ out) {
  // LDS layout (67072 B total -> 2 blocks/CU by LDS):
  //  [0,8192)      A1: normalized x tile [64][64] bf16, XOR-swizzled
  //  [8192,36864)  B1: w_down tile [224][64] bf16, XOR-swizzled
  //  [0,29696)     B2: w_up tile [64][232] bf16 (reuses A1/B1 space in phase 3)
  //  [36864,66560) G : bottleneck activations [64][232] bf16 (pad 224->232)
  //  [66560,67072) mu/rsig per row
  __shared__ __align__(16) char smem[67072];
  char* A1 = smem;
  char* B1 = smem + 8192;
  char* B2 = smem;
  char* G  = smem + 36864;
  float* smu = reinterpret_cast<float*>(smem + 66560);
  float* srs = smu + 64;

  const int tid  = threadIdx.x;
  const int wave = tid >> 6;
  const int lane = tid & 63;
  const int lm   = lane & 15;   // MFMA 16-index (A row / B col / D col)
  const int lk   = lane >> 4;   // MFMA k-group
  const int tb   = blockIdx.x * BM;
  const float alpha = alpha_p[0];

  // ---- Phase 1: LayerNorm statistics (each wave: 8 rows, 64-lane reduce) ----
  for (int r = 0; r < 8; ++r) {
    const int row = wave * 8 + r;
    const float4* xr = reinterpret_cast<const float4*>(x + (size_t)(tb + row) * HID);
    float s = 0.f, s2 = 0.f;
#pragma unroll
    for (int i = 0; i < 14; ++i) {          // 14*64 float4 = 3584 floats
      float4 v = xr[lane + 64 * i];
      s  += v.x + v.y + v.z + v.w;
      s2 += v.x * v.x + v.y * v.y + v.z * v.z + v.w * v.w;
    }
#pragma unroll
    for (int off = 32; off > 0; off >>= 1) {
      s  += __shfl_xor(s, off);
      s2 += __shfl_xor(s2, off);
    }
    if (lane == 0) {
      float mu  = s * (1.f / HID);
      float var = s2 * (1.f / HID) - mu * mu;
      smu[row] = mu;
      srs[row] = rsqrtf(var + 1e-5f);
    }
  }
  __syncthreads();

  // GEMM1 wave tiling: mg in {0,1} -> 2 m-tiles (32 rows); ng in 0..3 over 14
  // n-tiles split 4/4/3/3.
  const int mg  = wave >> 2;
  const int ng  = wave & 3;
  const int cnt = (ng < 2) ? 4 : 3;
  const int nst = (ng < 2) ? ng * 4 : ng * 3 + 2;   // 0,4,8,11

  f32x4 acc[2][4];
#pragma unroll
  for (int a = 0; a < 2; ++a)
#pragma unroll
    for (int b = 0; b < 4; ++b)
      acc[a][b] = (f32x4){0.f, 0.f, 0.f, 0.f};

  const int arow = tid >> 3, ac = tid & 7;     // A-staging: 64 rows x 8 chunks
  const float amu = smu[arow], ars = srs[arow];

  // ---- Phase 2: down GEMM, K = 3584 in 56 steps of BK=64 ----
  for (int kt = 0; kt < 56; ++kt) {
    const int k0 = kt * 64;
    {  // stage A: re-read x (L2/L3 hit), normalize, bf16-pack, swizzled store
      const int k = k0 + ac * 8;
      const float4* xp = reinterpret_cast<const float4*>(x + (size_t)(tb + arow) * HID + k);
      float4 v0 = xp[0], v1 = xp[1];
      const float4 g0 = *reinterpret_cast<const float4*>(gamma + k);
      const float4 g1 = *reinterpret_cast<const float4*>(gamma + k + 4);
      const float4 b0 = *reinterpret_cast<const float4*>(beta + k);
      const float4 b1 = *reinterpret_cast<const float4*>(beta + k + 4);
      ushort8 o;
      o[0] = f2bf((v0.x - amu) * ars * g0.x + b0.x);
      o[1] = f2bf((v0.y - amu) * ars * g0.y + b0.y);
      o[2] = f2bf((v0.z - amu) * ars * g0.z + b0.z);
      o[3] = f2bf((v0.w - amu) * ars * g0.w + b0.w);
      o[4] = f2bf((v1.x - amu) * ars * g1.x + b1.x);
      o[5] = f2bf((v1.y - amu) * ars * g1.y + b1.y);
      o[6] = f2bf((v1.z - amu) * ars * g1.z + b1.z);
      o[7] = f2bf((v1.w - amu) * ars * g1.w + b1.w);
      *reinterpret_cast<ushort8*>(A1 + arow * 128 + ((ac * 16) ^ ((arow & 7) << 4))) = o;
    }
    // stage B1: w_down bf16 tile [224 n][64 k], swizzled
#pragma unroll
    for (int ii = 0; ii < 4; ++ii) {
      const int idx = tid + ii * 512;
      if (idx < 1792) {
        const int n = idx >> 3, c = idx & 7;
        ushort8 w = *reinterpret_cast<const ushort8*>(wd + (size_t)n * HID + k0 + c * 8);
        *reinterpret_cast<ushort8*>(B1 + n * 128 + ((c * 16) ^ ((n & 7) << 4))) = w;
      }
    }
    __syncthreads();
#pragma unroll
    for (int ks = 0; ks < 2; ++ks) {
      const int cc = ks * 4 + lk;
      const int r0 = mg * 32 + lm;
      const int r1 = r0 + 16;
      short8 a0 = *reinterpret_cast<const short8*>(A1 + r0 * 128 + ((cc * 16) ^ ((r0 & 7) << 4)));
      short8 a1 = *reinterpret_cast<const short8*>(A1 + r1 * 128 + ((cc * 16) ^ ((r1 & 7) << 4)));
#pragma unroll
      for (int ni = 0; ni < 4; ++ni) {
        if (ni < cnt) {
          const int n = (nst + ni) * 16 + lm;
          short8 b = *reinterpret_cast<const short8*>(B1 + n * 128 + ((cc * 16) ^ ((n & 7) << 4)));
          acc[0][ni] = __builtin_amdgcn_mfma_f32_16x16x32_bf16(a0, b, acc[0][ni], 0, 0, 0);
          acc[1][ni] = __builtin_amdgcn_mfma_f32_16x16x32_bf16(a1, b, acc[1][ni], 0, 0, 0);
        }
      }
    }
    __syncthreads();
  }

  // ---- GELU (exact, erf) + store bottleneck activations to LDS (bf16) ----
#pragma unroll
  for (int mt = 0; mt < 2; ++mt) {
    const int rowb = (mg * 2 + mt) * 16 + lk * 4;
#pragma unroll
    for (int ni = 0; ni < 4; ++ni) {
      if (ni < cnt) {
        const int col = (nst + ni) * 16 + lm;
#pragma unroll
        for (int r = 0; r < 4; ++r) {
          float v = acc[mt][ni][r];
          v = 0.5f * v * (1.f + erff(v * 0.70710678118f));
          *reinterpret_cast<unsigned short*>(G + (size_t)(rowb + r) * 464 + col * 2) = f2bf(v);
        }
      }
    }
  }
  __syncthreads();

  // Hoist GEMM2 A-fragments (g) into registers: reused for all 56 n-iters.
  short8 a2h[2][7];
#pragma unroll
  for (int mt = 0; mt < 2; ++mt) {
    const int row = (mg * 2 + mt) * 16 + lm;
#pragma unroll
    for (int ks = 0; ks < 7; ++ks)
      a2h[mt][ks] = *reinterpret_cast<const short8*>(G + row * 464 + ks * 64 + lk * 16);
  }

  // ---- Phase 3: up GEMM (K=224) + fused residual epilogue ----
  for (int it = 0; it < 56; ++it) {
    const int nb = it * 64;
    // stage w_up tile [64 n][224 k] bf16 (rows padded to 232)
#pragma unroll
    for (int ii = 0; ii < 4; ++ii) {
      const int idx = tid + ii * 512;
      const int n = idx >> 5, c = idx & 31;
      if (c < 28) {
        ushort8 w = *reinterpret_cast<const ushort8*>(wu + (size_t)(nb + n) * RDIM + c * 8);
        *reinterpret_cast<ushort8*>(B2 + n * 464 + c * 16) = w;
      }
    }
    __syncthreads();
    f32x4 acc2[2];
    acc2[0] = (f32x4){0.f, 0.f, 0.f, 0.f};
    acc2[1] = (f32x4){0.f, 0.f, 0.f, 0.f};
    const int nloc = ng * 16 + lm;
#pragma unroll
    for (int ks = 0; ks < 7; ++ks) {
      short8 b = *reinterpret_cast<const short8*>(B2 + nloc * 464 + ks * 64 + lk * 16);
      acc2[0] = __builtin_amdgcn_mfma_f32_16x16x32_bf16(a2h[0][ks], b, acc2[0], 0, 0, 0);
      acc2[1] = __builtin_amdgcn_mfma_f32_16x16x32_bf16(a2h[1][ks], b, acc2[1], 0, 0, 0);
    }
    const int col = nb + ng * 16 + lm;
#pragma unroll
    for (int mt = 0; mt < 2; ++mt) {
      const int rowg = tb + (mg * 2 + mt) * 16 + lk * 4;
#pragma unroll
      for (int r = 0; r < 4; ++r) {
        const size_t o = (size_t)(rowg + r) * HID + col;
        out[o] = x[o] + alpha * acc2[mt][r];
      }
    }
    __syncthreads();
  }
}

extern "C" void kernel_launch(void* const* d_in, const int* in_sizes, int n_in,
                              void* d_out, int out_size, void* d_ws, size_t ws_size,
                              hipStream_t stream) {
  const float* x     = (const float*)d_in[0];
  const float* gamma = (const float*)d_in[1];
  const float* beta  = (const float*)d_in[2];
  const float* wdf   = (const float*)d_in[3];
  const float* wuf   = (const float*)d_in[4];
  const float* alpha = (const float*)d_in[5];
  unsigned short* wdb = (unsigned short*)d_ws;               // bf16 w_down
  unsigned short* wub = wdb + (size_t)RDIM * HID;            // bf16 w_up

  // convert both weight matrices (2 * 200704 float4 work items)
  hipLaunchKernelGGL(prep_weights, dim3(1568), dim3(256), 0, stream,
                     wdf, wuf, wdb, wub);
  // 16384 tokens / 64 per block
  hipLaunchKernelGGL(fused_adapter, dim3(256), dim3(512), 0, stream,
                     x, gamma, beta, wdb, wub, alpha, (float*)d_out);
}